// Round 4
// baseline (84.134 us; speedup 1.0000x reference)
//
#include <hip/hip_runtime.h>
#include <hip/hip_bf16.h>
#include <math.h>

// B=32, T=256, E=C=256, MIN_CONTEXT=64, FUTURE_STEPS=12
// S0=192, NROW=6144, K=256. G = P·X^T (6144x6144), bucketed exp-sums.
// t in [181,192) are singleton tail buckets; bucket0 = t<181. N_terms=71616.

#define NROW 6144
#define TAIL0 181
#define NTERMS 71616.0f
#define LOG2E 1.44269504088896340736f
#define SHIFT2 92.33248261689366f   // 64 * log2(e)

typedef __attribute__((ext_vector_type(8))) short short8;
typedef __attribute__((ext_vector_type(4))) float f32x4;

__device__ __forceinline__ ushort f2bf(float f) {
  union { float f; uint32_t u; } v; v.f = f;
  uint32_t u = v.u;
  return (ushort)((u + 0x7FFFu + ((u >> 16) & 1u)) >> 16);
}
__device__ __forceinline__ float b2f(ushort h) {
  union { uint32_t u; float f; } v; v.u = ((uint32_t)h) << 16; return v.f;
}
// exp(x - 64) = exp2(x*log2e - 64*log2e)
__device__ __forceinline__ float expsh(float x) {
  return exp2f(fmaf(x, LOG2E, -SHIFT2));
}

// async global->LDS, 16B per lane; lds dst must be wave-uniform base
__device__ __forceinline__ void gload16(const ushort* g, ushort* l) {
  __builtin_amdgcn_global_load_lds((const __attribute__((address_space(1))) void*)g,
                                   (__attribute__((address_space(3))) void*)l, 16, 0, 0);
}

// ---- A0+A1 fused: casts.
// blocks [0,1536): X[t*32+j][k] = bf16(ctx[j][63+t][k]); blocks [1536,1792): Wt.
__global__ __launch_bounds__(256) void k_cast(const float* __restrict__ ctx,
                                              const float* __restrict__ W,
                                              ushort* __restrict__ X,
                                              ushort* __restrict__ Wt) {
  int bi = blockIdx.x;
  if (bi < 1536) {
    int idx = bi * 256 + threadIdx.x;   // 393216 float4 chunks
    int row = idx >> 6, f4 = idx & 63;  // row = t*32+j
    int j = row & 31, t = row >> 5;
    float4 f = *(const float4*)(ctx + ((size_t)(j * 256 + 63 + t)) * 256 + f4 * 4);
    ushort4 o;
    o.x = f2bf(f.x); o.y = f2bf(f.y); o.z = f2bf(f.z); o.w = f2bf(f.w);
    ((ushort4*)(X + (size_t)row * 256))[f4] = o;
  } else {
    int c = bi - 1536, e = threadIdx.x;
    Wt[c * 256 + e] = f2bf(W[e * 256 + c]);
  }
}

// ---- A2: P = emb_slice @ W. Block = 1 row-tile (16 rows), A cast once into LDS,
// 4 waves x 4 col-tiles each. XOR-swizzled LDS (chunk ^ (row&7)) -> 2-way reads.
__global__ __launch_bounds__(256) void k_proj(const float* __restrict__ emb,
                                              const ushort* __restrict__ Wt,
                                              ushort* __restrict__ P) {
  __shared__ ushort Al[16 * 256];  // 8KB
  int tid = threadIdx.x;
  int rt = blockIdx.x;             // 384 row tiles
#pragma unroll
  for (int q = 0; q < 4; ++q) {
    int cc = tid + q * 256;
    int rw = cc >> 6, f4 = cc & 63;
    int u = rt * 16 + rw, b = u / 192, urow = u - b * 192;
    float4 f = *(const float4*)(emb + ((size_t)(b * 256 + 64 + urow)) * 256 + f4 * 4);
    ushort4 o;
    o.x = f2bf(f.x); o.y = f2bf(f.y); o.z = f2bf(f.z); o.w = f2bf(f.w);
    int c8 = f4 >> 1;
    *(ushort4*)&Al[rw * 256 + ((c8 ^ (rw & 7)) * 8) + (f4 & 1) * 4] = o;
  }
  __syncthreads();

  int w = tid >> 6, l = tid & 63;
  int fr = l & 15, kb = l >> 4;
  short8 af[8];
#pragma unroll
  for (int kk = 0; kk < 8; ++kk) {
    int c8 = kk * 4 + kb;
    af[kk] = *(const short8*)&Al[fr * 256 + (c8 ^ (fr & 7)) * 8];
  }
#pragma unroll
  for (int i = 0; i < 4; ++i) {
    int ct = w * 4 + i;
    const short8* bp = (const short8*)(Wt + (size_t)(ct * 16 + fr) * 256);
    f32x4 acc = {0.f, 0.f, 0.f, 0.f};
#pragma unroll
    for (int kk = 0; kk < 8; ++kk)
      acc = __builtin_amdgcn_mfma_f32_16x16x32_bf16(af[kk], bp[kk * 4 + kb], acc, 0, 0, 0);
#pragma unroll
    for (int r = 0; r < 4; ++r)
      P[(size_t)(rt * 16 + kb * 4 + r) * 256 + ct * 16 + fr] = f2bf(acc[r]);
  }
}

// ---- B: 128x128-tile GEMM G = P·X^T, double-buffered LDS, one barrier per K-step.
// Next tile's global_load_lds issued BEFORE current tile's ds_read+MFMA so the
// barrier's vmcnt(0) drain lands ~250 cycles after issue (latency hidden).
// LDS [128][32] row-major, 2-bit XOR swizzle via pre-swizzled global source.
__global__ __launch_bounds__(256) void k_scores(const ushort* __restrict__ P,
                                                const ushort* __restrict__ X,
                                                float* __restrict__ sum0,
                                                float* __restrict__ tail,
                                                float* __restrict__ pos) {
  __shared__ ushort Al[2][128 * 32];   // 2 x 8KB
  __shared__ ushort Bl[2][128 * 32];
  int tid = threadIdx.x;
  int w = tid >> 6, l = tid & 63;
  int wr = w >> 1, wc = w & 1;
  int rowbase = blockIdx.x * 128;
  int colbase = blockIdx.y * 128;

  // staging chunks: c0 = w*128+l, c1 = c0+64; row=c>>2, src slot = (c&3)^((c>>3)&3)
  int c0 = w * 128 + l;
  int r0 = c0 >> 2, s0 = (c0 & 3) ^ ((c0 >> 3) & 3);
  int c1 = c0 + 64;
  int r1 = c1 >> 2, s1 = (c1 & 3) ^ ((c1 >> 3) & 3);
  const ushort* gA0 = P + (size_t)(rowbase + r0) * 256 + s0 * 8;
  const ushort* gA1 = P + (size_t)(rowbase + r1) * 256 + s1 * 8;
  const ushort* gB0 = X + (size_t)(colbase + r0) * 256 + s0 * 8;
  const ushort* gB1 = X + (size_t)(colbase + r1) * 256 + s1 * 8;
  ushort* lA0 = &Al[0][w * 1024];   // wave-uniform bases (chunk w*128)
  ushort* lB0 = &Bl[0][w * 1024];

  int fr = l & 15, kb = l >> 4;
  int kbs = kb ^ ((fr >> 1) & 3);

  f32x4 acc[4][4];
#pragma unroll
  for (int m = 0; m < 4; ++m)
#pragma unroll
    for (int n = 0; n < 4; ++n) acc[m][n] = {0.f, 0.f, 0.f, 0.f};

  // prologue: stage K-step 0 into buffer 0
  gload16(gA0, lA0);
  gload16(gA1, lA0 + 512);
  gload16(gB0, lB0);
  gload16(gB1, lB0 + 512);
  __syncthreads();

  for (int kk = 0; kk < 8; ++kk) {
    int cur = kk & 1;
    if (kk < 7) {   // issue next stage, stays in flight during MFMA below
      int nb = cur ^ 1;
      gload16(gA0 + (kk + 1) * 32, lA0 + nb * 4096);
      gload16(gA1 + (kk + 1) * 32, lA0 + nb * 4096 + 512);
      gload16(gB0 + (kk + 1) * 32, lB0 + nb * 4096);
      gload16(gB1 + (kk + 1) * 32, lB0 + nb * 4096 + 512);
    }
    const ushort* Ab = &Al[cur][0];
    const ushort* Bb = &Bl[cur][0];
    short8 af[4], bf[4];
#pragma unroll
    for (int m = 0; m < 4; ++m)
      af[m] = *(const short8*)&Ab[(wr * 64 + m * 16 + fr) * 32 + kbs * 8];
#pragma unroll
    for (int n = 0; n < 4; ++n)
      bf[n] = *(const short8*)&Bb[(wc * 64 + n * 16 + fr) * 32 + kbs * 8];
#pragma unroll
    for (int m = 0; m < 4; ++m)
#pragma unroll
      for (int n = 0; n < 4; ++n)
        acc[m][n] = __builtin_amdgcn_mfma_f32_16x16x32_bf16(af[m], bf[n], acc[m][n], 0, 0, 0);
    __syncthreads();   // drains this step's prefetch; protects buffer reuse
  }

  // ---- epilogue: positives + exp bucket sums
  // C/D: row_in_frag = kb*4+r, col_in_frag = fr
  int t0g = blockIdx.y * 4 + wc * 2;
  bool all0 = blockIdx.y < 45;   // whole block in bucket0
#pragma unroll
  for (int m = 0; m < 4; ++m) {
    int rowg = rowbase + wr * 64 + m * 16 + kb * 4;
#pragma unroll
    for (int r = 0; r < 4; ++r) {
      int u = rowg + r;
      int b = u / 192;
      int urow = u - b * 192;
#pragma unroll
      for (int n = 0; n < 4; ++n) {
        int colg = colbase + wc * 64 + n * 16 + fr;
        int dt = urow - (colg >> 5);
        if ((colg & 31) == b && dt >= 0 && dt < 12)
          pos[u * 12 + dt] = acc[m][n][r];
      }
      if (all0) {
        float v = expsh(acc[m][0][r]) + expsh(acc[m][1][r]) +
                  expsh(acc[m][2][r]) + expsh(acc[m][3][r]);
        v += __shfl_xor(v, 1); v += __shfl_xor(v, 2);
        v += __shfl_xor(v, 4); v += __shfl_xor(v, 8);
        if (fr == 0) atomicAdd(&sum0[u], v);
      } else {
        float v0 = expsh(acc[m][0][r]) + expsh(acc[m][1][r]);
        float v1 = expsh(acc[m][2][r]) + expsh(acc[m][3][r]);
        v0 += __shfl_xor(v0, 1); v0 += __shfl_xor(v0, 2);
        v0 += __shfl_xor(v0, 4); v0 += __shfl_xor(v0, 8);
        v1 += __shfl_xor(v1, 1); v1 += __shfl_xor(v1, 2);
        v1 += __shfl_xor(v1, 4); v1 += __shfl_xor(v1, 8);
        if (fr == 0) {
          if (t0g + 1 < TAIL0) {
            atomicAdd(&sum0[u], v0 + v1);
          } else if (t0g < TAIL0) {
            atomicAdd(&sum0[u], v0);
            tail[(size_t)(t0g + 1 - TAIL0) * NROW + u] = v1;
          } else {
            tail[(size_t)(t0g - TAIL0) * NROW + u] = v0;
            tail[(size_t)(t0g + 1 - TAIL0) * NROW + u] = v1;
          }
        }
      }
    }
  }
}

// ---- D: per-row loss terms + global reduce
__global__ void k_loss(const float* __restrict__ sum0, const float* __restrict__ tail,
                       const float* __restrict__ pos, float* __restrict__ acc) {
  int u = blockIdx.x * 256 + threadIdx.x;
  int urow = u % 192;
  int smax = urow < 11 ? urow : 11;
  float denom = sum0[u];
  float local = 0.f;
  for (int s = 11; s >= 0; --s) {
    if (s < 11) denom += tail[(size_t)(10 - s) * NROW + u];
    if (s <= smax)
      local += pos[u * 12 + s] - 64.f - __logf(denom) + __logf(32.f * (float)(192 - s));
  }
  float v = local;
  v += __shfl_xor(v, 1);  v += __shfl_xor(v, 2);  v += __shfl_xor(v, 4);
  v += __shfl_xor(v, 8);  v += __shfl_xor(v, 16); v += __shfl_xor(v, 32);
  __shared__ float red[4];
  if ((threadIdx.x & 63) == 0) red[threadIdx.x >> 6] = v;
  __syncthreads();
  if (threadIdx.x == 0) atomicAdd(acc, red[0] + red[1] + red[2] + red[3]);
}

__global__ void k_final(const float* __restrict__ acc, float* __restrict__ out) {
  if (threadIdx.x == 0) out[0] = -acc[0] * (1.0f / NTERMS);
}

extern "C" void kernel_launch(void* const* d_in, const int* in_sizes, int n_in,
                              void* d_out, int out_size, void* d_ws, size_t ws_size,
                              hipStream_t stream) {
  const float* emb = (const float*)d_in[0];
  const float* ctx = (const float*)d_in[1];
  const float* W   = (const float*)d_in[2];
  char* ws = (char*)d_ws;
  ushort* P    = (ushort*)(ws + 0);         // 6144x256 bf16
  ushort* X    = (ushort*)(ws + 3145728);   // 6144x256 bf16
  ushort* Wt   = (ushort*)(ws + 6291456);   // 256x256 bf16
  float*  sum0 = (float*)(ws + 6422528);    // 6144 f32
  float*  acc  = (float*)(ws + 6447104);    // 1 f32
  float*  tail = (float*)(ws + 6447360);    // 11x6144 f32
  float*  pos  = (float*)(ws + 6717696);    // 6144x12 f32

  hipMemsetAsync(sum0, 0, 24580, stream);   // sum0 + acc

  k_cast<<<1792, 256, 0, stream>>>(ctx, W, X, Wt);
  k_proj<<<384, 256, 0, stream>>>(emb, Wt, P);
  k_scores<<<dim3(48, 48), 256, 0, stream>>>(P, X, sum0, tail, pos);
  k_loss<<<24, 256, 0, stream>>>(sum0, tail, pos, acc);
  k_final<<<1, 64, 0, stream>>>(acc, (float*)d_out);
}